// Round 5
// baseline (210.504 us; speedup 1.0000x reference)
//
#include <hip/hip_runtime.h>
#include <hip/hip_cooperative_groups.h>

namespace cg = cooperative_groups;

#define SEQ 512
#define MD  1024
#define RK  128

typedef __attribute__((ext_vector_type(8))) short  bf16x8;
typedef __attribute__((ext_vector_type(4))) float  floatx4;
typedef __attribute__((ext_vector_type(4))) unsigned int uint4v;
typedef __attribute__((ext_vector_type(4))) unsigned short ushortx4;

__device__ inline unsigned short f2bf(float f) {
    union { float f; unsigned u; } v; v.f = f;
    unsigned r = v.u + 0x7fffu + ((v.u >> 16) & 1u);   // RNE, inputs are normal
    return (unsigned short)(r >> 16);
}

#define LDB  136    // dist tile row stride (bf16): 16B rows, /16B odd -> 2-way alias only
#define REDW 2112   // 16 * 132 floats per wave partial (proj reduce)

// One cooperative dispatch, 512 blocks x 256 threads (4 waves), three phases:
//  P0: blocks 0..31   transpose proj -> Pt (bf16 128x1024)
//  P1: blocks 0..255  T = bf16(batch @ proj) + row norms (MFMA, K-quarter/wave)
//  P2: blocks 0..511  D[b,i,j] = nI + nJ - 2*(T_i . T_j)   (MFMA 64x64 tiles)
__global__ __launch_bounds__(256, 2) void fused_probe(
    const float* __restrict__ batch, const float* __restrict__ proj,
    unsigned short* __restrict__ Pt, unsigned short* __restrict__ T,
    float* __restrict__ Nrm, float* __restrict__ out)
{
    __shared__ float smem[8832];   // 35.3 KB pool, shared across phases

    const int t   = threadIdx.x;
    const int bid = blockIdx.x;
    cg::grid_group grid = cg::this_grid();

    // ---------------- Phase 0: transpose proj -> Pt ----------------
    if (bid < 32) {
        float* Ls = smem;                 // 64 k x 64 n, pad 68
        const int k0 = (bid >> 1) * 64;
        const int n0 = (bid & 1) * 64;
        {
            int kr = t >> 2, nc = (t & 3) * 16;
            #pragma unroll
            for (int c = 0; c < 4; ++c) {
                float4 v = *(const float4*)(proj + (size_t)(k0 + kr) * RK + n0 + nc + c * 4);
                *(float4*)(Ls + kr * 68 + nc + c * 4) = v;
            }
        }
        __syncthreads();
        {
            int nl = t >> 2, kh = (t & 3) * 16;
            unsigned short tmp[16];
            #pragma unroll
            for (int kk = 0; kk < 16; ++kk)
                tmp[kk] = f2bf(Ls[(kh + kk) * 68 + nl]);
            *(uint4v*)(Pt + (size_t)(n0 + nl) * MD + k0 + kh)     = *(uint4v*)(tmp);
            *(uint4v*)(Pt + (size_t)(n0 + nl) * MD + k0 + kh + 8) = *(uint4v*)(tmp + 8);
        }
        __threadfence();
    }
    grid.sync();

    // ---------------- Phase 1: proj MFMA (T + norms) ----------------
    if (bid < 256) {
        float* Red = smem;                // 4 waves x REDW
        const int w    = t >> 6;
        const int l    = t & 63;
        const int lm   = l & 15;
        const int quad = l >> 4;
        const int r0   = bid * 16;

        floatx4 acc[8];
        #pragma unroll
        for (int i = 0; i < 8; ++i) acc[i] = (floatx4){0.f, 0.f, 0.f, 0.f};

        const float*          arow = batch + (size_t)(r0 + lm) * MD + w * 256 + quad * 8;
        const unsigned short* brow = Pt + (size_t)lm * MD + w * 256 + quad * 8;

        #pragma unroll
        for (int s = 0; s < 8; ++s) {
            float4 a0 = *(const float4*)(arow + s * 32);
            float4 a1 = *(const float4*)(arow + s * 32 + 4);
            bf16x8 av;
            av[0] = (short)f2bf(a0.x); av[1] = (short)f2bf(a0.y);
            av[2] = (short)f2bf(a0.z); av[3] = (short)f2bf(a0.w);
            av[4] = (short)f2bf(a1.x); av[5] = (short)f2bf(a1.y);
            av[6] = (short)f2bf(a1.z); av[7] = (short)f2bf(a1.w);
            #pragma unroll
            for (int nt = 0; nt < 8; ++nt) {
                bf16x8 bv = *(const bf16x8*)(brow + (size_t)nt * 16 * MD + s * 32);
                acc[nt] = __builtin_amdgcn_mfma_f32_16x16x32_bf16(av, bv, acc[nt], 0, 0, 0);
            }
        }

        // dump per-wave partials; stride 132 -> 2-way bank alias only (free)
        #pragma unroll
        for (int nt = 0; nt < 8; ++nt) {
            #pragma unroll
            for (int r = 0; r < 4; ++r)
                Red[w * REDW + (quad * 4 + r) * 132 + nt * 16 + lm] = acc[nt][r];
        }
        __syncthreads();

        // reduce 4 partials; thread -> (row = t>>4, 8 cols at (t&15)*8)
        {
            const int row = t >> 4;
            const int c8  = (t & 15) * 8;
            float4 s0 = {0.f,0.f,0.f,0.f}, s1 = {0.f,0.f,0.f,0.f};
            #pragma unroll
            for (int ww = 0; ww < 4; ++ww) {
                float4 p0 = *(const float4*)(Red + ww * REDW + row * 132 + c8);
                float4 p1 = *(const float4*)(Red + ww * REDW + row * 132 + c8 + 4);
                s0.x += p0.x; s0.y += p0.y; s0.z += p0.z; s0.w += p0.w;
                s1.x += p1.x; s1.y += p1.y; s1.z += p1.z; s1.w += p1.w;
            }
            unsigned short tmp[8];
            tmp[0] = f2bf(s0.x); tmp[1] = f2bf(s0.y); tmp[2] = f2bf(s0.z); tmp[3] = f2bf(s0.w);
            tmp[4] = f2bf(s1.x); tmp[5] = f2bf(s1.y); tmp[6] = f2bf(s1.z); tmp[7] = f2bf(s1.w);
            *(uint4v*)(T + (size_t)(r0 + row) * RK + c8) = *(uint4v*)tmp;

            // fused row norm across the 16 lanes owning the row
            float ss = s0.x*s0.x + s0.y*s0.y + s0.z*s0.z + s0.w*s0.w
                     + s1.x*s1.x + s1.y*s1.y + s1.z*s1.z + s1.w*s1.w;
            ss += __shfl_xor(ss, 1, 64);
            ss += __shfl_xor(ss, 2, 64);
            ss += __shfl_xor(ss, 4, 64);
            ss += __shfl_xor(ss, 8, 64);
            if ((t & 15) == 0) Nrm[r0 + row] = ss;
        }
        __threadfence();
    }
    grid.sync();

    // ---------------- Phase 2: dist MFMA ----------------
    {
        unsigned short* Ti = (unsigned short*)smem;       // 64 x LDB bf16
        unsigned short* Tj = Ti + 64 * LDB;
        float* nI = (float*)(Tj + 64 * LDB);
        float* nJ = nI + 64;

        const int w    = t >> 6;
        const int l    = t & 63;
        const int lm   = l & 15;
        const int quad = l >> 4;
        const int b  = bid >> 6;
        const int it = (bid >> 3) & 7;
        const int jt = bid & 7;
        const int i0 = it * 64, j0 = jt * 64;
        const unsigned short* Tb = T + (size_t)b * SEQ * RK;

        {   // stage both 64x128 bf16 tiles + norms
            int row = t >> 2, kq = (t & 3) * 32;
            const unsigned short* si = Tb + (size_t)(i0 + row) * RK + kq;
            const unsigned short* sj = Tb + (size_t)(j0 + row) * RK + kq;
            #pragma unroll
            for (int q = 0; q < 4; ++q) {
                *(uint4v*)(Ti + row * LDB + kq + q * 8) = *(const uint4v*)(si + q * 8);
                *(uint4v*)(Tj + row * LDB + kq + q * 8) = *(const uint4v*)(sj + q * 8);
            }
            if (t < 64)       nI[t]      = Nrm[(size_t)b * SEQ + i0 + t];
            else if (t < 128) nJ[t - 64] = Nrm[(size_t)b * SEQ + j0 + (t - 64)];
        }
        __syncthreads();

        floatx4 acc[4];
        #pragma unroll
        for (int i = 0; i < 4; ++i) acc[i] = (floatx4){0.f, 0.f, 0.f, 0.f};

        #pragma unroll
        for (int s = 0; s < 4; ++s) {
            bf16x8 av = *(const bf16x8*)(Ti + (w * 16 + lm) * LDB + s * 32 + quad * 8);
            #pragma unroll
            for (int nt = 0; nt < 4; ++nt) {
                bf16x8 bv = *(const bf16x8*)(Tj + (nt * 16 + lm) * LDB + s * 32 + quad * 8);
                acc[nt] = __builtin_amdgcn_mfma_f32_16x16x32_bf16(av, bv, acc[nt], 0, 0, 0);
            }
        }

        float niv[4];
        #pragma unroll
        for (int r = 0; r < 4; ++r) niv[r] = nI[w * 16 + quad * 4 + r];

        float* ob = out + ((size_t)b * SEQ + (i0 + w * 16)) * SEQ + j0;
        #pragma unroll
        for (int nt = 0; nt < 4; ++nt) {
            float njv = nJ[nt * 16 + lm];
            #pragma unroll
            for (int r = 0; r < 4; ++r) {
                ob[(size_t)(quad * 4 + r) * SEQ + nt * 16 + lm] =
                    niv[r] + njv - 2.f * acc[nt][r];
            }
        }
    }
}

extern "C" void kernel_launch(void* const* d_in, const int* in_sizes, int n_in,
                              void* d_out, int out_size, void* d_ws, size_t ws_size,
                              hipStream_t stream) {
    const float* batch = (const float*)d_in[0];   // (8, 512, 1024) fp32
    const float* proj  = (const float*)d_in[1];   // (1024, 128) fp32
    float* out = (float*)d_out;                   // (8, 512, 512) fp32

    unsigned short* T   = (unsigned short*)d_ws;                          // 1 MB bf16
    unsigned short* Pt  = (unsigned short*)((char*)d_ws + (1 << 20));     // 256 KB bf16
    float*          Nrm = (float*)((char*)d_ws + (1 << 20) + (1 << 18));  // 16 KB fp32

    void* args[] = { (void*)&batch, (void*)&proj, (void*)&Pt, (void*)&T,
                     (void*)&Nrm, (void*)&out };
    hipLaunchCooperativeKernel((const void*)fused_probe, dim3(512), dim3(256),
                               args, 0, stream);
}

// Round 6
// 153.021 us; speedup vs baseline: 1.3756x; 1.3756x over previous
//
#include <hip/hip_runtime.h>

#define SEQ 512
#define MD  1024
#define RK  128
#define MAGIC 0x13572468

typedef __attribute__((ext_vector_type(8))) short  bf16x8;
typedef __attribute__((ext_vector_type(4))) float  floatx4;
typedef __attribute__((ext_vector_type(4))) unsigned int uint4v;

__device__ inline unsigned short f2bf(float f) {
    union { float f; unsigned u; } v; v.f = f;
    unsigned r = v.u + 0x7fffu + ((v.u >> 16) & 1u);   // RNE, inputs are normal
    return (unsigned short)(r >> 16);
}

#define LDB  136    // dist tile row stride (bf16): 16B rows, /16B odd -> 2-way alias only
#define REDW 2112   // 16 * 132 floats per wave partial (proj reduce)

// Single dispatch, 512 blocks x 256 threads (4 waves). DAG sync via per-block
// release/acquire flags (device-scope atomics) -- NO grid-wide barrier.
//   role A (bid<32)  : transpose proj slice -> Pt, set f_pt[bid]
//   role B (bid<256) : wait f_pt[0..31]; T rows bid*16 + norms; set f_T[bid]
//   role C (all 512) : wait 8 f_T flags; dist 64x64 tile -> out
// Poisoned ws (0xAA) != MAGIC serves as the flags' "not ready" state.
__global__ __launch_bounds__(256, 2) void fused_all(
    const float* __restrict__ batch, const float* __restrict__ proj,
    unsigned short* __restrict__ Pt, unsigned short* __restrict__ T,
    float* __restrict__ Nrm, int* __restrict__ f_pt, int* __restrict__ f_T,
    float* __restrict__ out)
{
    __shared__ float smem[8832];   // 35.3 KB pool shared across phases

    const int t    = threadIdx.x;
    const int bid  = blockIdx.x;
    const int w    = t >> 6;
    const int l    = t & 63;
    const int lm   = l & 15;
    const int quad = l >> 4;

    // ---- Prefetch A-operands for proj phase (independent of Pt) ----
    float4 a0s[8], a1s[8];
    if (bid < 256) {
        const float* arow = batch + (size_t)(bid * 16 + lm) * MD + w * 256 + quad * 8;
        #pragma unroll
        for (int s = 0; s < 8; ++s) {
            a0s[s] = *(const float4*)(arow + s * 32);
            a1s[s] = *(const float4*)(arow + s * 32 + 4);
        }
    }

    // ---------------- Role A: transpose proj -> Pt ----------------
    if (bid < 32) {
        float* Ls = smem;                 // 64 k x 64 n, pad 68
        const int k0 = (bid >> 1) * 64;
        const int n0 = (bid & 1) * 64;
        {
            int kr = t >> 2, nc = (t & 3) * 16;
            #pragma unroll
            for (int c = 0; c < 4; ++c) {
                float4 v = *(const float4*)(proj + (size_t)(k0 + kr) * RK + n0 + nc + c * 4);
                *(float4*)(Ls + kr * 68 + nc + c * 4) = v;
            }
        }
        __syncthreads();
        {
            int nl = t >> 2, kh = (t & 3) * 16;
            unsigned short tmp[16];
            #pragma unroll
            for (int kk = 0; kk < 16; ++kk)
                tmp[kk] = f2bf(Ls[(kh + kk) * 68 + nl]);
            *(uint4v*)(Pt + (size_t)(n0 + nl) * MD + k0 + kh)     = *(uint4v*)(tmp);
            *(uint4v*)(Pt + (size_t)(n0 + nl) * MD + k0 + kh + 8) = *(uint4v*)(tmp + 8);
        }
        __syncthreads();                  // all stores drained (vmcnt0 at barrier)
        if (t == 0) {
            __threadfence();              // device-scope release of Pt
            atomicExch(f_pt + bid, MAGIC);
        }
        __syncthreads();                  // protect LDS reuse
    }

    // ---------------- Role B: T = bf16(batch @ proj) + norms ----------------
    if (bid < 256) {
        // acquire Pt
        if (t == 0) {
            #pragma unroll 1
            for (int i = 0; i < 32; ++i)
                while (atomicAdd(f_pt + i, 0) != MAGIC) __builtin_amdgcn_s_sleep(4);
        }
        __syncthreads();
        __threadfence();

        const int r0 = bid * 16;
        floatx4 acc[8];
        #pragma unroll
        for (int i = 0; i < 8; ++i) acc[i] = (floatx4){0.f, 0.f, 0.f, 0.f};

        const unsigned short* brow = Pt + (size_t)lm * MD + w * 256 + quad * 8;
        #pragma unroll
        for (int s = 0; s < 8; ++s) {
            bf16x8 av;
            av[0] = (short)f2bf(a0s[s].x); av[1] = (short)f2bf(a0s[s].y);
            av[2] = (short)f2bf(a0s[s].z); av[3] = (short)f2bf(a0s[s].w);
            av[4] = (short)f2bf(a1s[s].x); av[5] = (short)f2bf(a1s[s].y);
            av[6] = (short)f2bf(a1s[s].z); av[7] = (short)f2bf(a1s[s].w);
            #pragma unroll
            for (int nt = 0; nt < 8; ++nt) {
                bf16x8 bv = *(const bf16x8*)(brow + (size_t)nt * 16 * MD + s * 32);
                acc[nt] = __builtin_amdgcn_mfma_f32_16x16x32_bf16(av, bv, acc[nt], 0, 0, 0);
            }
        }

        // per-wave partials; stride 132 -> 2-way bank alias only (free)
        float* Red = smem;
        #pragma unroll
        for (int nt = 0; nt < 8; ++nt) {
            #pragma unroll
            for (int r = 0; r < 4; ++r)
                Red[w * REDW + (quad * 4 + r) * 132 + nt * 16 + lm] = acc[nt][r];
        }
        __syncthreads();

        // reduce 4 partials; thread -> (row = t>>4, 8 cols at (t&15)*8)
        {
            const int row = t >> 4;
            const int c8  = (t & 15) * 8;
            float4 s0 = {0.f,0.f,0.f,0.f}, s1 = {0.f,0.f,0.f,0.f};
            #pragma unroll
            for (int ww = 0; ww < 4; ++ww) {
                float4 p0 = *(const float4*)(Red + ww * REDW + row * 132 + c8);
                float4 p1 = *(const float4*)(Red + ww * REDW + row * 132 + c8 + 4);
                s0.x += p0.x; s0.y += p0.y; s0.z += p0.z; s0.w += p0.w;
                s1.x += p1.x; s1.y += p1.y; s1.z += p1.z; s1.w += p1.w;
            }
            unsigned short tmp[8];
            tmp[0] = f2bf(s0.x); tmp[1] = f2bf(s0.y); tmp[2] = f2bf(s0.z); tmp[3] = f2bf(s0.w);
            tmp[4] = f2bf(s1.x); tmp[5] = f2bf(s1.y); tmp[6] = f2bf(s1.z); tmp[7] = f2bf(s1.w);
            *(uint4v*)(T + (size_t)(r0 + row) * RK + c8) = *(uint4v*)tmp;

            float ss = s0.x*s0.x + s0.y*s0.y + s0.z*s0.z + s0.w*s0.w
                     + s1.x*s1.x + s1.y*s1.y + s1.z*s1.z + s1.w*s1.w;
            ss += __shfl_xor(ss, 1, 64);
            ss += __shfl_xor(ss, 2, 64);
            ss += __shfl_xor(ss, 4, 64);
            ss += __shfl_xor(ss, 8, 64);
            if ((t & 15) == 0) Nrm[r0 + row] = ss;
        }
        __syncthreads();                  // T/Nrm stores drained + Red reads done
        if (t == 0) {
            __threadfence();              // device-scope release of T/Nrm
            atomicExch(f_T + bid, MAGIC);
        }
        __syncthreads();                  // protect LDS reuse
    }

    // ---------------- Role C: dist 64x64 tile ----------------
    {
        const int b  = bid >> 6;
        const int it = (bid >> 3) & 7;
        const int jt = bid & 7;
        const int i0 = it * 64, j0 = jt * 64;

        // acquire the 8 T-producer flags this tile needs
        if (t == 0) {
            const int fi = b * 32 + it * 4;
            const int fj = b * 32 + jt * 4;
            #pragma unroll 1
            for (int i = 0; i < 4; ++i)
                while (atomicAdd(f_T + fi + i, 0) != MAGIC) __builtin_amdgcn_s_sleep(4);
            #pragma unroll 1
            for (int i = 0; i < 4; ++i)
                while (atomicAdd(f_T + fj + i, 0) != MAGIC) __builtin_amdgcn_s_sleep(4);
        }
        __syncthreads();
        __threadfence();

        unsigned short* Ti = (unsigned short*)smem;       // 64 x LDB bf16
        unsigned short* Tj = Ti + 64 * LDB;
        float* nI = (float*)(Tj + 64 * LDB);
        float* nJ = nI + 64;
        const unsigned short* Tb = T + (size_t)b * SEQ * RK;

        {   // stage both 64x128 bf16 tiles + norms
            int row = t >> 2, kq = (t & 3) * 32;
            const unsigned short* si = Tb + (size_t)(i0 + row) * RK + kq;
            const unsigned short* sj = Tb + (size_t)(j0 + row) * RK + kq;
            #pragma unroll
            for (int q = 0; q < 4; ++q) {
                *(uint4v*)(Ti + row * LDB + kq + q * 8) = *(const uint4v*)(si + q * 8);
                *(uint4v*)(Tj + row * LDB + kq + q * 8) = *(const uint4v*)(sj + q * 8);
            }
            if (t < 64)       nI[t]      = Nrm[(size_t)b * SEQ + i0 + t];
            else if (t < 128) nJ[t - 64] = Nrm[(size_t)b * SEQ + j0 + (t - 64)];
        }
        __syncthreads();

        floatx4 acc[4];
        #pragma unroll
        for (int i = 0; i < 4; ++i) acc[i] = (floatx4){0.f, 0.f, 0.f, 0.f};

        #pragma unroll
        for (int s = 0; s < 4; ++s) {
            bf16x8 av = *(const bf16x8*)(Ti + (w * 16 + lm) * LDB + s * 32 + quad * 8);
            #pragma unroll
            for (int nt = 0; nt < 4; ++nt) {
                bf16x8 bv = *(const bf16x8*)(Tj + (nt * 16 + lm) * LDB + s * 32 + quad * 8);
                acc[nt] = __builtin_amdgcn_mfma_f32_16x16x32_bf16(av, bv, acc[nt], 0, 0, 0);
            }
        }

        float niv[4];
        #pragma unroll
        for (int r = 0; r < 4; ++r) niv[r] = nI[w * 16 + quad * 4 + r];

        float* ob = out + ((size_t)b * SEQ + (i0 + w * 16)) * SEQ + j0;
        #pragma unroll
        for (int nt = 0; nt < 4; ++nt) {
            float njv = nJ[nt * 16 + lm];
            #pragma unroll
            for (int r = 0; r < 4; ++r) {
                ob[(size_t)(quad * 4 + r) * SEQ + nt * 16 + lm] =
                    niv[r] + njv - 2.f * acc[nt][r];
            }
        }
    }
}

extern "C" void kernel_launch(void* const* d_in, const int* in_sizes, int n_in,
                              void* d_out, int out_size, void* d_ws, size_t ws_size,
                              hipStream_t stream) {
    const float* batch = (const float*)d_in[0];   // (8, 512, 1024) fp32
    const float* proj  = (const float*)d_in[1];   // (1024, 128) fp32
    float* out = (float*)d_out;                   // (8, 512, 512) fp32

    char* ws = (char*)d_ws;
    unsigned short* T    = (unsigned short*)(ws);                 // 1 MB bf16
    unsigned short* Pt   = (unsigned short*)(ws + 1048576);       // 256 KB bf16
    float*          Nrm  = (float*)(ws + 1048576 + 262144);       // 16 KB fp32
    int*            f_pt = (int*)(ws + 1048576 + 262144 + 16384); // 128 B
    int*            f_T  = (int*)(ws + 1048576 + 262144 + 16384 + 256); // 1 KB

    fused_all<<<512, 256, 0, stream>>>(batch, proj, Pt, T, Nrm, f_pt, f_T, out);
}

// Round 7
// 139.685 us; speedup vs baseline: 1.5070x; 1.0955x over previous
//
#include <hip/hip_runtime.h>

#define SEQ 512
#define MD  1024
#define RK  128
#define MAGIC 0x13572468

typedef __attribute__((ext_vector_type(8))) short  bf16x8;
typedef __attribute__((ext_vector_type(4))) float  floatx4;
typedef __attribute__((ext_vector_type(4))) unsigned int uint4v;

__device__ inline unsigned short f2bf(float f) {
    union { float f; unsigned u; } v; v.f = f;
    unsigned r = v.u + 0x7fffu + ((v.u >> 16) & 1u);   // RNE, inputs are normal
    return (unsigned short)(r >> 16);
}

#define LDB  136    // dist tile row stride (bf16): 16B rows, /16B odd -> 2-way alias only
#define REDW 2112   // 16 * 132 floats per wave partial (proj reduce)

// Single dispatch, 512 blocks x 256 threads (4 waves). DAG sync via per-block
// release/acquire flags. Consumers poll with AGENT-scope atomic LOADS (no RMW)
// spread across wave-0 lanes -- one load instr per poll round per block.
//   role A (bid<32)  : transpose proj slice -> Pt, release f_pt[bid]
//   role B (bid<256) : acquire f_pt[0..32); T rows bid*16 + norms; release f_T[bid]
//   role C (all 512) : acquire 8 f_T flags; dist 64x64 tile -> out
// Poisoned ws (0xAA) != MAGIC is the "not ready" state; flags are write-once.
__global__ __launch_bounds__(256, 2) void fused_all(
    const float* __restrict__ batch, const float* __restrict__ proj,
    unsigned short* __restrict__ Pt, unsigned short* __restrict__ T,
    float* __restrict__ Nrm, int* __restrict__ f_pt, int* __restrict__ f_T,
    float* __restrict__ out)
{
    __shared__ float smem[8832];   // 35.3 KB pool shared across phases

    const int t    = threadIdx.x;
    const int bid  = blockIdx.x;
    const int w    = t >> 6;
    const int l    = t & 63;
    const int lm   = l & 15;
    const int quad = l >> 4;

    // ---- Prefetch A-operands for proj phase (independent of Pt) ----
    float4 a0s[8], a1s[8];
    if (bid < 256) {
        const float* arow = batch + (size_t)(bid * 16 + lm) * MD + w * 256 + quad * 8;
        #pragma unroll
        for (int s = 0; s < 8; ++s) {
            a0s[s] = *(const float4*)(arow + s * 32);
            a1s[s] = *(const float4*)(arow + s * 32 + 4);
        }
    }

    // ---------------- Role A: transpose proj -> Pt ----------------
    if (bid < 32) {
        float* Ls = smem;                 // 64 k x 64 n, pad 68
        const int k0 = (bid >> 1) * 64;
        const int n0 = (bid & 1) * 64;
        {
            int kr = t >> 2, nc = (t & 3) * 16;
            #pragma unroll
            for (int c = 0; c < 4; ++c) {
                float4 v = *(const float4*)(proj + (size_t)(k0 + kr) * RK + n0 + nc + c * 4);
                *(float4*)(Ls + kr * 68 + nc + c * 4) = v;
            }
        }
        __syncthreads();
        {
            int nl = t >> 2, kh = (t & 3) * 16;
            unsigned short tmp[16];
            #pragma unroll
            for (int kk = 0; kk < 16; ++kk)
                tmp[kk] = f2bf(Ls[(kh + kk) * 68 + nl]);
            *(uint4v*)(Pt + (size_t)(n0 + nl) * MD + k0 + kh)     = *(uint4v*)(tmp);
            *(uint4v*)(Pt + (size_t)(n0 + nl) * MD + k0 + kh + 8) = *(uint4v*)(tmp + 8);
        }
        __syncthreads();                  // all Pt stores drained at barrier
        if (t == 0) {
            __threadfence();              // device-scope release of Pt
            atomicExch(f_pt + bid, MAGIC);
        }
        __syncthreads();                  // protect LDS reuse
    }

    // ---------------- Role B: T = bf16(batch @ proj) + norms ----------------
    if (bid < 256) {
        // acquire Pt: wave 0, lane i polls flag i (coherent load, no RMW)
        if (t < 64) {
            const int idx = t & 31;
            while (true) {
                int v = __hip_atomic_load(f_pt + idx, __ATOMIC_RELAXED,
                                          __HIP_MEMORY_SCOPE_AGENT);
                if (__ballot(v != MAGIC) == 0ull) break;
                __builtin_amdgcn_s_sleep(8);
            }
        }
        __syncthreads();
        __threadfence();

        const int r0 = bid * 16;
        floatx4 acc[8];
        #pragma unroll
        for (int i = 0; i < 8; ++i) acc[i] = (floatx4){0.f, 0.f, 0.f, 0.f};

        const unsigned short* brow = Pt + (size_t)lm * MD + w * 256 + quad * 8;
        #pragma unroll
        for (int s = 0; s < 8; ++s) {
            bf16x8 av;
            av[0] = (short)f2bf(a0s[s].x); av[1] = (short)f2bf(a0s[s].y);
            av[2] = (short)f2bf(a0s[s].z); av[3] = (short)f2bf(a0s[s].w);
            av[4] = (short)f2bf(a1s[s].x); av[5] = (short)f2bf(a1s[s].y);
            av[6] = (short)f2bf(a1s[s].z); av[7] = (short)f2bf(a1s[s].w);
            #pragma unroll
            for (int nt = 0; nt < 8; ++nt) {
                bf16x8 bv = *(const bf16x8*)(brow + (size_t)nt * 16 * MD + s * 32);
                acc[nt] = __builtin_amdgcn_mfma_f32_16x16x32_bf16(av, bv, acc[nt], 0, 0, 0);
            }
        }

        // per-wave partials; stride 132 -> 2-way bank alias only (free)
        float* Red = smem;
        #pragma unroll
        for (int nt = 0; nt < 8; ++nt) {
            #pragma unroll
            for (int r = 0; r < 4; ++r)
                Red[w * REDW + (quad * 4 + r) * 132 + nt * 16 + lm] = acc[nt][r];
        }
        __syncthreads();

        // reduce 4 partials; thread -> (row = t>>4, 8 cols at (t&15)*8)
        {
            const int row = t >> 4;
            const int c8  = (t & 15) * 8;
            float4 s0 = {0.f,0.f,0.f,0.f}, s1 = {0.f,0.f,0.f,0.f};
            #pragma unroll
            for (int ww = 0; ww < 4; ++ww) {
                float4 p0 = *(const float4*)(Red + ww * REDW + row * 132 + c8);
                float4 p1 = *(const float4*)(Red + ww * REDW + row * 132 + c8 + 4);
                s0.x += p0.x; s0.y += p0.y; s0.z += p0.z; s0.w += p0.w;
                s1.x += p1.x; s1.y += p1.y; s1.z += p1.z; s1.w += p1.w;
            }
            unsigned short tmp[8];
            tmp[0] = f2bf(s0.x); tmp[1] = f2bf(s0.y); tmp[2] = f2bf(s0.z); tmp[3] = f2bf(s0.w);
            tmp[4] = f2bf(s1.x); tmp[5] = f2bf(s1.y); tmp[6] = f2bf(s1.z); tmp[7] = f2bf(s1.w);
            *(uint4v*)(T + (size_t)(r0 + row) * RK + c8) = *(uint4v*)tmp;

            float ss = s0.x*s0.x + s0.y*s0.y + s0.z*s0.z + s0.w*s0.w
                     + s1.x*s1.x + s1.y*s1.y + s1.z*s1.z + s1.w*s1.w;
            ss += __shfl_xor(ss, 1, 64);
            ss += __shfl_xor(ss, 2, 64);
            ss += __shfl_xor(ss, 4, 64);
            ss += __shfl_xor(ss, 8, 64);
            if ((t & 15) == 0) Nrm[r0 + row] = ss;
        }
        __syncthreads();                  // T/Nrm stores drained + Red reads done
        if (t == 0) {
            __threadfence();              // device-scope release of T/Nrm
            atomicExch(f_T + bid, MAGIC);
        }
        __syncthreads();                  // protect LDS reuse
    }

    // ---------------- Role C: dist 64x64 tile ----------------
    {
        const int b  = bid >> 6;
        const int it = (bid >> 3) & 7;
        const int jt = bid & 7;
        const int i0 = it * 64, j0 = jt * 64;

        // acquire the 8 T-producer flags: lanes 0..7 each watch one flag
        if (t < 64) {
            const int fi = b * 32 + it * 4;
            const int fj = b * 32 + jt * 4;
            int idx;
            if (t < 4)      idx = fi + t;
            else if (t < 8) idx = fj + (t - 4);
            else            idx = fi;          // harmless duplicate
            while (true) {
                int v = __hip_atomic_load(f_T + idx, __ATOMIC_RELAXED,
                                          __HIP_MEMORY_SCOPE_AGENT);
                if (__ballot(v != MAGIC) == 0ull) break;
                __builtin_amdgcn_s_sleep(8);
            }
        }
        __syncthreads();
        __threadfence();

        unsigned short* Ti = (unsigned short*)smem;       // 64 x LDB bf16
        unsigned short* Tj = Ti + 64 * LDB;
        float* nI = (float*)(Tj + 64 * LDB);
        float* nJ = nI + 64;
        const unsigned short* Tb = T + (size_t)b * SEQ * RK;

        {   // stage both 64x128 bf16 tiles + norms
            int row = t >> 2, kq = (t & 3) * 32;
            const unsigned short* si = Tb + (size_t)(i0 + row) * RK + kq;
            const unsigned short* sj = Tb + (size_t)(j0 + row) * RK + kq;
            #pragma unroll
            for (int q = 0; q < 4; ++q) {
                *(uint4v*)(Ti + row * LDB + kq + q * 8) = *(const uint4v*)(si + q * 8);
                *(uint4v*)(Tj + row * LDB + kq + q * 8) = *(const uint4v*)(sj + q * 8);
            }
            if (t < 64)       nI[t]      = Nrm[(size_t)b * SEQ + i0 + t];
            else if (t < 128) nJ[t - 64] = Nrm[(size_t)b * SEQ + j0 + (t - 64)];
        }
        __syncthreads();

        floatx4 acc[4];
        #pragma unroll
        for (int i = 0; i < 4; ++i) acc[i] = (floatx4){0.f, 0.f, 0.f, 0.f};

        #pragma unroll
        for (int s = 0; s < 4; ++s) {
            bf16x8 av = *(const bf16x8*)(Ti + (w * 16 + lm) * LDB + s * 32 + quad * 8);
            #pragma unroll
            for (int nt = 0; nt < 4; ++nt) {
                bf16x8 bv = *(const bf16x8*)(Tj + (nt * 16 + lm) * LDB + s * 32 + quad * 8);
                acc[nt] = __builtin_amdgcn_mfma_f32_16x16x32_bf16(av, bv, acc[nt], 0, 0, 0);
            }
        }

        float niv[4];
        #pragma unroll
        for (int r = 0; r < 4; ++r) niv[r] = nI[w * 16 + quad * 4 + r];

        float* ob = out + ((size_t)b * SEQ + (i0 + w * 16)) * SEQ + j0;
        #pragma unroll
        for (int nt = 0; nt < 4; ++nt) {
            float njv = nJ[nt * 16 + lm];
            #pragma unroll
            for (int r = 0; r < 4; ++r) {
                ob[(size_t)(quad * 4 + r) * SEQ + nt * 16 + lm] =
                    niv[r] + njv - 2.f * acc[nt][r];
            }
        }
    }
}

extern "C" void kernel_launch(void* const* d_in, const int* in_sizes, int n_in,
                              void* d_out, int out_size, void* d_ws, size_t ws_size,
                              hipStream_t stream) {
    const float* batch = (const float*)d_in[0];   // (8, 512, 1024) fp32
    const float* proj  = (const float*)d_in[1];   // (1024, 128) fp32
    float* out = (float*)d_out;                   // (8, 512, 512) fp32

    char* ws = (char*)d_ws;
    unsigned short* T    = (unsigned short*)(ws);                 // 1 MB bf16
    unsigned short* Pt   = (unsigned short*)(ws + 1048576);       // 256 KB bf16
    float*          Nrm  = (float*)(ws + 1048576 + 262144);       // 16 KB fp32
    int*            f_pt = (int*)(ws + 1048576 + 262144 + 16384); // 128 B
    int*            f_T  = (int*)(ws + 1048576 + 262144 + 16384 + 256); // 1 KB

    fused_all<<<512, 256, 0, stream>>>(batch, proj, Pt, T, Nrm, f_pt, f_T, out);
}

// Round 8
// 77.099 us; speedup vs baseline: 2.7303x; 1.8118x over previous
//
#include <hip/hip_runtime.h>

#define SEQ 512
#define MD  1024
#define RK  128

typedef __attribute__((ext_vector_type(8))) short  bf16x8;
typedef __attribute__((ext_vector_type(4))) float  floatx4;
typedef __attribute__((ext_vector_type(4))) unsigned int uint4v;
typedef __attribute__((ext_vector_type(4))) unsigned short ushortx4;

__device__ inline unsigned short f2bf(float f) {
    union { float f; unsigned u; } v; v.f = f;
    unsigned r = v.u + 0x7fffu + ((v.u >> 16) & 1u);   // RNE, inputs are normal
    return (unsigned short)(r >> 16);
}

#define REDW 2112   // 16 * 132 floats per wave partial (proj reduce)

// ---------- Kernel 1: T = bf16(batch @ proj) + row norms, via MFMA ----------
// 256 blocks x 512 threads (8 waves). Block owns 16 rows; wave w owns a K-eighth.
// A-frags: fp32 dwordx4 from batch + cvt. B-frags: 8 strided dword gathers from
// fp32 proj (L2/L3-resident, shared by all blocks) -- NO transpose kernel, no
// inter-kernel Pt dependency. One barrier before the conflict-free reduce.
__global__ __launch_bounds__(512, 2) void proj_direct(
    const float* __restrict__ batch, const float* __restrict__ proj,
    unsigned short* __restrict__ T, float* __restrict__ Nrm)
{
    __shared__ float Red[8 * REDW];   // 67.6 KB

    const int t    = threadIdx.x;
    const int w    = t >> 6;
    const int l    = t & 63;
    const int lm   = l & 15;
    const int quad = l >> 4;
    const int r0   = blockIdx.x * 16;

    floatx4 acc[8];
    #pragma unroll
    for (int i = 0; i < 8; ++i) acc[i] = (floatx4){0.f, 0.f, 0.f, 0.f};

    const float* arow = batch + (size_t)(r0 + lm) * MD + w * 128 + quad * 8;

    #pragma unroll
    for (int s = 0; s < 4; ++s) {
        // A fragment: lane holds A[m=lm][k = w*128 + s*32 + quad*8 + j]
        float4 a0 = *(const float4*)(arow + s * 32);
        float4 a1 = *(const float4*)(arow + s * 32 + 4);
        bf16x8 av;
        av[0] = (short)f2bf(a0.x); av[1] = (short)f2bf(a0.y);
        av[2] = (short)f2bf(a0.z); av[3] = (short)f2bf(a0.w);
        av[4] = (short)f2bf(a1.x); av[5] = (short)f2bf(a1.y);
        av[6] = (short)f2bf(a1.z); av[7] = (short)f2bf(a1.w);

        // B fragments: lane needs proj[k][n], n = nt*16+lm, k = kb+j (stride RK)
        const float* bk = proj + (size_t)(w * 128 + s * 32 + quad * 8) * RK + lm;
        #pragma unroll
        for (int nt = 0; nt < 8; ++nt) {
            const float* bp = bk + nt * 16;
            bf16x8 bv;
            #pragma unroll
            for (int j = 0; j < 8; ++j)
                bv[j] = (short)f2bf(bp[(size_t)j * RK]);
            acc[nt] = __builtin_amdgcn_mfma_f32_16x16x32_bf16(av, bv, acc[nt], 0, 0, 0);
        }
    }

    // dump per-wave partials; row stride 132 -> 2-way bank alias only (free)
    #pragma unroll
    for (int nt = 0; nt < 8; ++nt) {
        #pragma unroll
        for (int r = 0; r < 4; ++r) {
            Red[w * REDW + (quad * 4 + r) * 132 + nt * 16 + lm] = acc[nt][r];
        }
    }
    __syncthreads();

    // conflict-free b128 reduce: thread -> (row = t>>5, col4 = (t&31)*4)
    {
        const int row  = t >> 5;
        const int col4 = (t & 31) * 4;
        float4 s4 = {0.f, 0.f, 0.f, 0.f};
        #pragma unroll
        for (int ww = 0; ww < 8; ++ww) {
            float4 p = *(const float4*)(Red + ww * REDW + row * 132 + col4);
            s4.x += p.x; s4.y += p.y; s4.z += p.z; s4.w += p.w;
        }
        unsigned short tmp[4];
        tmp[0] = f2bf(s4.x); tmp[1] = f2bf(s4.y);
        tmp[2] = f2bf(s4.z); tmp[3] = f2bf(s4.w);
        *(ushortx4*)(T + (size_t)(r0 + row) * RK + col4) = *(ushortx4*)tmp;

        // fused row norm: reduce ||T_row||^2 across the 32 lanes owning the row
        float ss = s4.x * s4.x + s4.y * s4.y + s4.z * s4.z + s4.w * s4.w;
        ss += __shfl_xor(ss, 1,  64);
        ss += __shfl_xor(ss, 2,  64);
        ss += __shfl_xor(ss, 4,  64);
        ss += __shfl_xor(ss, 8,  64);
        ss += __shfl_xor(ss, 16, 64);
        if ((t & 31) == 0) Nrm[r0 + row] = ss;
    }
}

// ---------- Kernel 2: D[b,i,j] = nI + nJ - 2 * (T_i . T_j), via MFMA ----------
// Grid (8 jt, 8 it, 8 b), 256 threads = 4 waves; 64x64 tile; wave w -> 16 i-rows.
#define LDB 136   // 128 + 8 bf16 pad: 16B rows, stride/16B odd -> 2-way alias only

__global__ __launch_bounds__(256) void dist_mfma(
    const unsigned short* __restrict__ T, const float* __restrict__ Nrm,
    float* __restrict__ out)
{
    __shared__ unsigned short Ti[64 * LDB];
    __shared__ unsigned short Tj[64 * LDB];
    __shared__ float nI[64], nJ[64];

    const int t    = threadIdx.x;
    const int w    = t >> 6;
    const int l    = t & 63;
    const int lm   = l & 15;
    const int quad = l >> 4;
    const int jt = blockIdx.x, it = blockIdx.y, b = blockIdx.z;
    const int i0 = it * 64, j0 = jt * 64;
    const unsigned short* Tb = T + (size_t)b * SEQ * RK;

    {   // stage both 64x128 bf16 tiles + norms
        int row = t >> 2, kq = (t & 3) * 32;
        const unsigned short* si = Tb + (size_t)(i0 + row) * RK + kq;
        const unsigned short* sj = Tb + (size_t)(j0 + row) * RK + kq;
        #pragma unroll
        for (int q = 0; q < 4; ++q) {
            *(uint4v*)(Ti + row * LDB + kq + q * 8) = *(const uint4v*)(si + q * 8);
            *(uint4v*)(Tj + row * LDB + kq + q * 8) = *(const uint4v*)(sj + q * 8);
        }
        if (t < 64)       nI[t]      = Nrm[(size_t)b * SEQ + i0 + t];
        else if (t < 128) nJ[t - 64] = Nrm[(size_t)b * SEQ + j0 + (t - 64)];
    }
    __syncthreads();

    floatx4 acc[4];
    #pragma unroll
    for (int i = 0; i < 4; ++i) acc[i] = (floatx4){0.f, 0.f, 0.f, 0.f};

    #pragma unroll
    for (int s = 0; s < 4; ++s) {
        bf16x8 av = *(const bf16x8*)(Ti + (w * 16 + lm) * LDB + s * 32 + quad * 8);
        #pragma unroll
        for (int nt = 0; nt < 4; ++nt) {
            bf16x8 bv = *(const bf16x8*)(Tj + (nt * 16 + lm) * LDB + s * 32 + quad * 8);
            acc[nt] = __builtin_amdgcn_mfma_f32_16x16x32_bf16(av, bv, acc[nt], 0, 0, 0);
        }
    }

    float niv[4];
    #pragma unroll
    for (int r = 0; r < 4; ++r) niv[r] = nI[w * 16 + quad * 4 + r];

    float* ob = out + ((size_t)b * SEQ + (i0 + w * 16)) * SEQ + j0;
    #pragma unroll
    for (int nt = 0; nt < 4; ++nt) {
        float njv = nJ[nt * 16 + lm];
        #pragma unroll
        for (int r = 0; r < 4; ++r) {
            ob[(size_t)(quad * 4 + r) * SEQ + nt * 16 + lm] =
                niv[r] + njv - 2.f * acc[nt][r];
        }
    }
}

extern "C" void kernel_launch(void* const* d_in, const int* in_sizes, int n_in,
                              void* d_out, int out_size, void* d_ws, size_t ws_size,
                              hipStream_t stream) {
    const float* batch = (const float*)d_in[0];   // (8, 512, 1024) fp32
    const float* proj  = (const float*)d_in[1];   // (1024, 128) fp32
    float* out = (float*)d_out;                   // (8, 512, 512) fp32

    unsigned short* T   = (unsigned short*)d_ws;                      // 1 MB bf16
    float*          Nrm = (float*)((char*)d_ws + (1 << 20));          // 16 KB fp32

    proj_direct<<<256, 512, 0, stream>>>(batch, proj, T, Nrm);
    dist_mfma<<<dim3(8, 8, 8), 256, 0, stream>>>(T, Nrm, out);
}